// Round 11
// baseline (3613.812 us; speedup 1.0000x reference)
//
#include <hip/hip_runtime.h>
#include <math.h>

// BiometricLSTM: 2-layer LSTM, B=512, T=2048, I=3, H=64, fp32 in/out. Output = final h2 (B,64).
//
// R11: K-split quads + in-lane updates + ONE barrier/iter.
// Lessons R8-R10: total dot work per CU-iter is invariant (~384 cyc/SIMD); what
// varies is overhead. R10's wave specialization idled waves and still hit the
// AGPR tax (VGPR=76 < 108 demand). This design keeps every wave dotting every
// iter, updates states in-lane (no gather barrier / gbuf roundtrip), and caps
// per-lane weights at 64 half2 (L1) / 32 half2 (L0).
//
// 512 blocks x 512 threads (8 waves), 1 seq/block, 2 blocks/CU.
//   waves 0-3: L0 step it.   wave w owns elems [16w,16w+16); quad lanes split K=64
//     into 16-wide slices of all 4 gate rows of one elem (32 half2 weights).
//   waves 4-7: L1 step it-1. same elem layout; quad lanes split K=128 over the
//     concatenated [Wih1.h1[it-1] | Whh1.h2[it-2]] (64 half2 weights).
// Quad-combine partial sums via __shfl_xor(1,2) (DPP, no LDS). Every lane of the
// quad redundantly computes activation+c+h (no extra issue cost: lanes, not
// instructions); lane ksub==0 writes h to LDS (f16). ONE __syncthreads per iter:
// all intra-iter reads (h1[it-1], h2[it-2]) were written >=1 barrier ago; writes
// (h1buf[cur], h2buf[prev]) are never read in the same iter. wid%4 puts one L0
// and one L1 wave per SIMD (balanced).

typedef _Float16 half2_t __attribute__((ext_vector_type(2)));

constexpr int TT = 2048;

__device__ __forceinline__ float fast_sigmoid(float x) {
    return 1.0f / (1.0f + __expf(-x));
}

// overflow-safe tanh: c can reach O(100s); exp(-2|x|) underflows harmlessly to 0 -> +/-1
__device__ __forceinline__ float fast_tanh(float x) {
    float ax = fabsf(x);
    float t  = __expf(-2.0f * ax);
    return copysignf((1.0f - t) / (1.0f + t), x);
}

__device__ __forceinline__ float dot2acc(half2_t a, half2_t b, float c) {
#if __has_builtin(__builtin_amdgcn_fdot2)
    return __builtin_amdgcn_fdot2(a, b, c, false);
#else
    c = fmaf((float)a[0], (float)b[0], c);
    return fmaf((float)a[1], (float)b[1], c);
#endif
}

__device__ __forceinline__ half2_t h2cast(float v) {
    return __builtin_bit_cast(half2_t, v);
}

__global__ __launch_bounds__(512) void lstm2_fused(
    const float* __restrict__ x,
    const float* __restrict__ Wih0, const float* __restrict__ Whh0,
    const float* __restrict__ bih0, const float* __restrict__ bhh0,
    const float* __restrict__ Wih1, const float* __restrict__ Whh1,
    const float* __restrict__ bih1, const float* __restrict__ bhh1,
    float* __restrict__ out)
{
    __shared__ __align__(16) float    xs4[TT * 4];    // 32 KB, stride-4 x
    __shared__ __align__(16) _Float16 h1buf[2][64];   // [parity][elem]
    __shared__ __align__(16) _Float16 h2buf[2][64];

    const int tid  = threadIdx.x;
    const int lane = tid & 63;
    const int wid  = tid >> 6;
    const bool isL1 = (wid >= 4);
    const int elem = ((wid & 3) << 4) + (lane >> 2);  // this quad's element
    const int ksub = lane & 3;                        // K-slice within the quad

    // ---- preload x: global (T,3) packed -> LDS stride 4 ----
    {
        const float* xg = x + (size_t)blockIdx.x * (TT * 3);
        for (int idx = tid; idx < TT * 3; idx += 512) {
            int t = idx / 3;              // magic-mul, no HW divide
            int c = idx - 3 * t;
            xs4[t * 4 + c] = xg[idx];
        }
    }
    // ---- zero h double-buffers ----
    if (tid < 128)          ((_Float16*)h1buf)[tid] = (_Float16)0.0f;
    else if (tid < 256)     ((_Float16*)h2buf)[tid - 128] = (_Float16)0.0f;

    // ---- weights (packed half2, registers) ----
    // L0 lane: 4 gates x 16 cols  -> w[g*8  + q], q<8   (32 half2)
    // L1 lane: 4 gates x 32 cols  -> w[g*16 + q], q<16  (64 half2)
    half2_t w[64];
    float wx0[4], wx1[4], wx2[4];   // L0 only: Wih0 rows
    float bias[4];
    if (!isL1) {
        #pragma unroll
        for (int g = 0; g < 4; ++g) {
            const int row = g * 64 + elem;
            const float4* src = (const float4*)(Whh0 + (size_t)row * 64 + ksub * 16);
            #pragma unroll
            for (int u = 0; u < 4; ++u) {
                float4 v = src[u];
                w[g*8 + 2*u+0] = half2_t{(_Float16)v.x, (_Float16)v.y};
                w[g*8 + 2*u+1] = half2_t{(_Float16)v.z, (_Float16)v.w};
            }
            wx0[g] = Wih0[row*3+0]; wx1[g] = Wih0[row*3+1]; wx2[g] = Wih0[row*3+2];
            bias[g] = bih0[row] + bhh0[row];
        }
    } else {
        const float* base = (ksub < 2) ? Wih1 : Whh1;
        const int coff = (ksub & 1) * 32;
        #pragma unroll
        for (int g = 0; g < 4; ++g) {
            const int row = g * 64 + elem;
            const float4* src = (const float4*)(base + (size_t)row * 64 + coff);
            #pragma unroll
            for (int u = 0; u < 8; ++u) {
                float4 v = src[u];
                w[g*16 + 2*u+0] = half2_t{(_Float16)v.x, (_Float16)v.y};
                w[g*16 + 2*u+1] = half2_t{(_Float16)v.z, (_Float16)v.w};
            }
            bias[g] = bih1[row] + bhh1[row];
        }
    }

    float c_state = 0.0f;   // per-quad redundant cell state (L0 or L1)

    __syncthreads();

    // iter it: L0 computes step it (it<TT): h1[it] = f(h1[it-1], x[it]).
    //          L1 computes step it-1 (it>=1): h2[it-1] = f(h1[it-1], h2[it-2]).
    // Parities: h1[t] at t&1; h2[t] at t&1. One barrier per iter.
    for (int it = 0; it <= TT; ++it) {
        const int cur  = it & 1;
        const int prev = cur ^ 1;

        if (!isL1) {
            if (it < TT) {
                // h1[it-1] slice [ksub*16, +16) halves = 32 B
                const float4* hp = (const float4*)((const char*)h1buf[prev] + ksub * 32);
                float4 v0 = hp[0], v1 = hp[1];
                half2_t hh[8];
                hh[0]=h2cast(v0.x); hh[1]=h2cast(v0.y); hh[2]=h2cast(v0.z); hh[3]=h2cast(v0.w);
                hh[4]=h2cast(v1.x); hh[5]=h2cast(v1.y); hh[6]=h2cast(v1.z); hh[7]=h2cast(v1.w);

                float s[4];
                #pragma unroll
                for (int g = 0; g < 4; ++g) {
                    float a = 0.f, b = 0.f;
                    #pragma unroll
                    for (int q = 0; q < 4; ++q) {
                        a = dot2acc(hh[2*q+0], w[g*8 + 2*q+0], a);
                        b = dot2acc(hh[2*q+1], w[g*8 + 2*q+1], b);
                    }
                    float t = a + b;
                    t += __shfl_xor(t, 1);
                    t += __shfl_xor(t, 2);
                    s[g] = t;
                }
                float4 xv = ((const float4*)xs4)[it];
                float pi = s[0] + bias[0] + wx0[0]*xv.x + wx1[0]*xv.y + wx2[0]*xv.z;
                float pf = s[1] + bias[1] + wx0[1]*xv.x + wx1[1]*xv.y + wx2[1]*xv.z;
                float pg = s[2] + bias[2] + wx0[2]*xv.x + wx1[2]*xv.y + wx2[2]*xv.z;
                float po = s[3] + bias[3] + wx0[3]*xv.x + wx1[3]*xv.y + wx2[3]*xv.z;
                float iv = fast_sigmoid(pi), fv = fast_sigmoid(pf);
                float gv = fast_tanh(pg),    ov = fast_sigmoid(po);
                c_state = fmaf(fv, c_state, iv * gv);
                float hv = ov * fast_tanh(c_state);
                if (ksub == 0) h1buf[cur][elem] = (_Float16)hv;     // h1[it]
            }
        } else {
            if (it >= 1) {
                // concat input [h1[it-1] | h2[it-2]]: ksub<2 -> h1 halves, else h2
                const char* hb = (ksub < 2) ? (const char*)h1buf[prev]
                                            : (const char*)h2buf[cur];
                const float4* hp = (const float4*)(hb + (ksub & 1) * 64);
                float4 v0 = hp[0], v1 = hp[1], v2 = hp[2], v3 = hp[3];
                half2_t hh[16];
                hh[0]=h2cast(v0.x);  hh[1]=h2cast(v0.y);  hh[2]=h2cast(v0.z);  hh[3]=h2cast(v0.w);
                hh[4]=h2cast(v1.x);  hh[5]=h2cast(v1.y);  hh[6]=h2cast(v1.z);  hh[7]=h2cast(v1.w);
                hh[8]=h2cast(v2.x);  hh[9]=h2cast(v2.y);  hh[10]=h2cast(v2.z); hh[11]=h2cast(v2.w);
                hh[12]=h2cast(v3.x); hh[13]=h2cast(v3.y); hh[14]=h2cast(v3.z); hh[15]=h2cast(v3.w);

                float s[4];
                #pragma unroll
                for (int g = 0; g < 4; ++g) {
                    float a = 0.f, b = 0.f;
                    #pragma unroll
                    for (int q = 0; q < 8; ++q) {
                        a = dot2acc(hh[2*q+0], w[g*16 + 2*q+0], a);
                        b = dot2acc(hh[2*q+1], w[g*16 + 2*q+1], b);
                    }
                    float t = a + b;
                    t += __shfl_xor(t, 1);
                    t += __shfl_xor(t, 2);
                    s[g] = t;
                }
                float pi = s[0] + bias[0];
                float pf = s[1] + bias[1];
                float pg = s[2] + bias[2];
                float po = s[3] + bias[3];
                float iv = fast_sigmoid(pi), fv = fast_sigmoid(pf);
                float gv = fast_tanh(pg),    ov = fast_sigmoid(po);
                c_state = fmaf(fv, c_state, iv * gv);
                float hv = ov * fast_tanh(c_state);
                if (ksub == 0) {
                    h2buf[prev][elem] = (_Float16)hv;               // h2[it-1]
                    if (it == TT)
                        out[(size_t)blockIdx.x * 64 + elem] = hv;
                }
            }
        }
        __syncthreads();
    }
}

extern "C" void kernel_launch(void* const* d_in, const int* in_sizes, int n_in,
                              void* d_out, int out_size, void* d_ws, size_t ws_size,
                              hipStream_t stream) {
    const float* x    = (const float*)d_in[0];
    const float* Wih0 = (const float*)d_in[1];
    const float* Whh0 = (const float*)d_in[2];
    const float* bih0 = (const float*)d_in[3];
    const float* bhh0 = (const float*)d_in[4];
    const float* Wih1 = (const float*)d_in[5];
    const float* Whh1 = (const float*)d_in[6];
    const float* bih1 = (const float*)d_in[7];
    const float* bhh1 = (const float*)d_in[8];
    float* out = (float*)d_out;

    // 512 sequences, 1 per block -> 512 blocks; 512 threads (8 waves), 2 blocks/CU.
    lstm2_fused<<<512, 512, 0, stream>>>(x, Wih0, Whh0, bih0, bhh0,
                                         Wih1, Whh1, bih1, bhh1, out);
}

// Round 12
// 3280.264 us; speedup vs baseline: 1.1017x; 1.1017x over previous
//
#include <hip/hip_runtime.h>
#include <math.h>

// BiometricLSTM: 2-layer LSTM, B=512, T=2048, I=3, H=64, fp32 in/out. Output = final h2 (B,64).
//
// R12: MFMA batch-GEMM restructure. R5-R11 showed fp32/dot2 VALU economics floor
// at ~1.8 ms regardless of arrangement (issue-bound: dots + updates + allocator
// register-motion tax). MFMA changes the economics: 16 seqs/block makes the
// recurrent matvec a 16x256xK GEMM per step, and MFMA reads A/B natively from
// AGPRs -> tax-immune weights.
//
// 32 blocks x 512 threads (8 waves), 16 seqs/block.
//   waves 0-3 (wid<4):  L0 step it.   wave w owns gate-cols [16w,16w+16) of all
//     4 gate classes; 4 class-tiles x 2 K-frags = 8 MFMA (16x16x32 f16).
//   waves 4-7: L1 step it-1. same cols; K=128 concat [h1[it-1] | h2[it-2]],
//     4 class-tiles x 4 K-frags = 16 MFMA.
// C/D layout (col=lane&15, row=quad*4+reg): lane ends up with i,f,g,o preacts
// for 4 seqs x 1 elem across its 4 class accumulators -> in-lane state update
// (c_state f32x4 in regs), no gather, ONE barrier/step.
// h stored f16 in LDS, row stride 72 halves (144B): A-frag ds_read_b128 16B
// aligned, <=2-way banks (free). B-frags (weights, f16) in regs/AGPRs, loaded
// once. x read per-step from global (L2-resident; issued before LDS reads so
// latency overlaps MFMA).

typedef _Float16 half8 __attribute__((ext_vector_type(8)));
typedef float    f32x4 __attribute__((ext_vector_type(4)));

constexpr int TT = 2048;
constexpr int HSTR = 72;   // h row stride in halves (144 B): 16B-aligned frags, 2-way banks

// sigmoid = 1/(1+exp(-x)): 4 instr, saturates correctly at +-inf
__device__ __forceinline__ float fast_sigmoid(float x) {
    return 1.0f / (1.0f + __expf(-x));
}
// tanh = 1 - 2/(exp(2x)+1): 5 instr; x->+inf: exp->inf, rcp->0 -> 1;
// x->-inf: exp->0 -> 1-2 = -1. Overflow-safe without abs/copysign.
__device__ __forceinline__ float fast_tanh(float x) {
    return 1.0f - 2.0f / (__expf(2.0f * x) + 1.0f);
}

__device__ __forceinline__ half8 ld_frag(const _Float16* p) {
    return *(const half8*)p;
}

__global__ __launch_bounds__(512) void lstm2_fused(
    const float* __restrict__ x,
    const float* __restrict__ Wih0, const float* __restrict__ Whh0,
    const float* __restrict__ bih0, const float* __restrict__ bhh0,
    const float* __restrict__ Wih1, const float* __restrict__ Whh1,
    const float* __restrict__ bih1, const float* __restrict__ bhh1,
    float* __restrict__ out)
{
    __shared__ __align__(16) _Float16 h1a[2][16 * HSTR];   // [parity][seq*HSTR + elem]
    __shared__ __align__(16) _Float16 h2a[2][16 * HSTR];

    const int tid  = threadIdx.x;
    const int lane = tid & 63;
    const int wid  = tid >> 6;
    const int quad = lane >> 4;
    const int l16  = lane & 15;
    const bool isL1 = (wid >= 4);
    const int wgrp = wid & 3;
    const int j0   = wgrp * 16 + l16;       // gate-elem column this lane owns per class

    // ---- zero h double-buffers ----
    for (int idx = tid; idx < 2 * 16 * HSTR; idx += 512) {
        h1a[0][idx] = (_Float16)0.0f;       // covers h1a[0] and h1a[1] contiguously
        h2a[0][idx] = (_Float16)0.0f;
    }

    // ---- B-fragments (weights), loaded once. Lane holds W[c*64+j0][kf*32+quad*8 .. +8] ----
    half8 wfr[4][4];                        // [class][kfrag]; L0 uses kfrag 0..1
    #pragma unroll
    for (int c = 0; c < 4; ++c) {
        const int row = c * 64 + j0;
        if (!isL1) {
            #pragma unroll
            for (int f = 0; f < 2; ++f) {
                const float* p = Whh0 + (size_t)row * 64 + f * 32 + quad * 8;
                half8 h;
                #pragma unroll
                for (int u = 0; u < 8; ++u) h[u] = (_Float16)p[u];
                wfr[c][f] = h;
            }
        } else {
            #pragma unroll
            for (int f = 0; f < 4; ++f) {
                const float* base = (f < 2) ? Wih1 : Whh1;
                const float* p = base + (size_t)row * 64 + (f & 1) * 32 + quad * 8;
                half8 h;
                #pragma unroll
                for (int u = 0; u < 8; ++u) h[u] = (_Float16)p[u];
                wfr[c][f] = h;
            }
        }
    }
    // ---- per-lane scalars ----
    float bias[4];
    float wxa[4], wxb[4], wxc[4];           // L0 only: Wih0 row (c*64+j0)
    #pragma unroll
    for (int c = 0; c < 4; ++c) {
        const int row = c * 64 + j0;
        if (!isL1) {
            bias[c] = bih0[row] + bhh0[row];
            wxa[c] = Wih0[row*3+0]; wxb[c] = Wih0[row*3+1]; wxc[c] = Wih0[row*3+2];
        } else {
            bias[c] = bih1[row] + bhh1[row];
        }
    }
    // x pointers for this lane's 4 seqs (seq = quad*4 + r)
    const float* xp[4];
    #pragma unroll
    for (int r = 0; r < 4; ++r)
        xp[r] = x + ((size_t)(blockIdx.x * 16 + quad * 4 + r) * TT) * 3;

    f32x4 cst = {0.f, 0.f, 0.f, 0.f};       // cell state for 4 seqs (this lane's quad rows)

    __syncthreads();

    // iter it: L0 computes step it (it<TT); L1 computes step it-1 (it>=1).
    // h1[t] at parity t&1; h2[t] at parity t&1. ONE barrier per iteration.
    for (int it = 0; it <= TT; ++it) {
        const int cur  = it & 1;
        const int prev = cur ^ 1;

        if (!isL1) {
            if (it < TT) {
                // x loads first (VMEM latency overlaps LDS + MFMA)
                float xr[4][3];
                #pragma unroll
                for (int r = 0; r < 4; ++r) {
                    const float* p = xp[r] + it * 3;
                    xr[r][0] = p[0]; xr[r][1] = p[1]; xr[r][2] = p[2];
                }
                // A-frags: lane = seq l16, k = f*32 + quad*8
                const _Float16* hb = h1a[prev] + l16 * HSTR + quad * 8;
                half8 a0 = ld_frag(hb);
                half8 a1 = ld_frag(hb + 32);
                f32x4 acc[4];
                #pragma unroll
                for (int c = 0; c < 4; ++c) {
                    f32x4 z = {0.f, 0.f, 0.f, 0.f};
                    z = __builtin_amdgcn_mfma_f32_16x16x32_f16(a0, wfr[c][0], z, 0, 0, 0);
                    z = __builtin_amdgcn_mfma_f32_16x16x32_f16(a1, wfr[c][1], z, 0, 0, 0);
                    acc[c] = z;
                }
                // in-lane update: reg r = seq quad*4+r, col j0
                #pragma unroll
                for (int r = 0; r < 4; ++r) {
                    float pi = acc[0][r] + bias[0] + wxa[0]*xr[r][0] + wxb[0]*xr[r][1] + wxc[0]*xr[r][2];
                    float pf = acc[1][r] + bias[1] + wxa[1]*xr[r][0] + wxb[1]*xr[r][1] + wxc[1]*xr[r][2];
                    float pg = acc[2][r] + bias[2] + wxa[2]*xr[r][0] + wxb[2]*xr[r][1] + wxc[2]*xr[r][2];
                    float po = acc[3][r] + bias[3] + wxa[3]*xr[r][0] + wxb[3]*xr[r][1] + wxc[3]*xr[r][2];
                    float iv = fast_sigmoid(pi), fv = fast_sigmoid(pf);
                    float gv = fast_tanh(pg),    ov = fast_sigmoid(po);
                    float cs = fmaf(fv, cst[r], iv * gv);
                    cst[r] = cs;
                    h1a[cur][(quad * 4 + r) * HSTR + j0] = (_Float16)(ov * fast_tanh(cs));
                }
            }
        } else {
            if (it >= 1) {
                // A-frags: k 0..63 from h1[it-1] (parity prev), k 64..127 from h2[it-2] (parity cur)
                const _Float16* hb1 = h1a[prev] + l16 * HSTR + quad * 8;
                const _Float16* hb2 = h2a[cur]  + l16 * HSTR + quad * 8;
                half8 a0 = ld_frag(hb1);
                half8 a1 = ld_frag(hb1 + 32);
                half8 a2 = ld_frag(hb2);
                half8 a3 = ld_frag(hb2 + 32);
                f32x4 acc[4];
                #pragma unroll
                for (int c = 0; c < 4; ++c) {
                    f32x4 z = {0.f, 0.f, 0.f, 0.f};
                    z = __builtin_amdgcn_mfma_f32_16x16x32_f16(a0, wfr[c][0], z, 0, 0, 0);
                    z = __builtin_amdgcn_mfma_f32_16x16x32_f16(a1, wfr[c][1], z, 0, 0, 0);
                    z = __builtin_amdgcn_mfma_f32_16x16x32_f16(a2, wfr[c][2], z, 0, 0, 0);
                    z = __builtin_amdgcn_mfma_f32_16x16x32_f16(a3, wfr[c][3], z, 0, 0, 0);
                    acc[c] = z;
                }
                #pragma unroll
                for (int r = 0; r < 4; ++r) {
                    float pi = acc[0][r] + bias[0];
                    float pf = acc[1][r] + bias[1];
                    float pg = acc[2][r] + bias[2];
                    float po = acc[3][r] + bias[3];
                    float iv = fast_sigmoid(pi), fv = fast_sigmoid(pf);
                    float gv = fast_tanh(pg),    ov = fast_sigmoid(po);
                    float cs = fmaf(fv, cst[r], iv * gv);
                    cst[r] = cs;
                    float hv = ov * fast_tanh(cs);
                    h2a[prev][(quad * 4 + r) * HSTR + j0] = (_Float16)hv;   // h2[it-1]
                    if (it == TT)
                        out[(size_t)(blockIdx.x * 16 + quad * 4 + r) * 64 + j0] = hv;
                }
            }
        }
        __syncthreads();
    }
}

extern "C" void kernel_launch(void* const* d_in, const int* in_sizes, int n_in,
                              void* d_out, int out_size, void* d_ws, size_t ws_size,
                              hipStream_t stream) {
    const float* x    = (const float*)d_in[0];
    const float* Wih0 = (const float*)d_in[1];
    const float* Whh0 = (const float*)d_in[2];
    const float* bih0 = (const float*)d_in[3];
    const float* bhh0 = (const float*)d_in[4];
    const float* Wih1 = (const float*)d_in[5];
    const float* Whh1 = (const float*)d_in[6];
    const float* bih1 = (const float*)d_in[7];
    const float* bhh1 = (const float*)d_in[8];
    float* out = (float*)d_out;

    // 512 sequences / 16 per block = 32 blocks; 512 threads (8 waves).
    lstm2_fused<<<32, 512, 0, stream>>>(x, Wih0, Whh0, bih0, bhh0,
                                        Wih1, Whh1, bih1, bhh1, out);
}

// Round 13
// 1392.734 us; speedup vs baseline: 2.5948x; 2.3553x over previous
//
#include <hip/hip_runtime.h>
#include <math.h>

// BiometricLSTM: 2-layer LSTM, B=512, T=2048, I=3, H=64, fp32 in/out. Output = final h2 (B,64).
//
// R13: spread chains over 4x more CUs, keep MFMA economics, kill the update
// concentration. R12 (32 blocks x 16 seqs) was latency-exposed (3840 cyc/iter,
// Occupancy 3%): per-step x loads on the critical path, ~640 cyc/SIMD of
// quarter-rate transcendental issue (2048 updates/CU-step x 10 trans each),
// barrier drain with nothing co-resident.
//
// 128 blocks x 4 seqs x 512 threads (8 waves): waves 0-3 = L0 (elem-tile w),
// waves 4-7 = L1 (one L0 + one L1 wave per SIMD).
// REPLICATED-ROW TRICK: A-frags read h with row addr (l16&3)*HSTR, so MFMA's
// 16 A-rows = the 4 seqs replicated 4x. In C/D layout (row = quad*4 + reg),
// reg r of EVERY quad = seq r -> lane(quad q, l16) selects reg q (3 cndmasks)
// and updates (seq q, col) fully in-lane: 1 update/lane, no shuffles, no
// gather barrier. Trans issue/SIMD: 160 cyc (was 640).
// x prefetched one iteration ahead (off critical path). HSTR=80 halves
// (160 B): A-frag bank aliasing <=2-way (free). Same parity/lag pipeline and
// fragment conventions as R12 (correctness-proven). ONE barrier/iter.

typedef _Float16 half8 __attribute__((ext_vector_type(8)));
typedef float    f32x4 __attribute__((ext_vector_type(4)));

constexpr int TT = 2048;
constexpr int HSTR = 80;   // h row stride in halves (160 B)

__device__ __forceinline__ float fast_sigmoid(float x) {
    return 1.0f / (1.0f + __expf(-x));
}
// tanh = 1 - 2/(exp(2x)+1): saturates correctly at +-inf (inf->1, 0->-1)
__device__ __forceinline__ float fast_tanh(float x) {
    return 1.0f - 2.0f / (__expf(2.0f * x) + 1.0f);
}

// select component q (q = lane's quad, 0..3) from an f32x4 accumulator
__device__ __forceinline__ float sel4(f32x4 v, int q) {
    float r = v[0];
    r = (q == 1) ? v[1] : r;
    r = (q == 2) ? v[2] : r;
    r = (q == 3) ? v[3] : r;
    return r;
}

__global__ __launch_bounds__(512) void lstm2_fused(
    const float* __restrict__ x,
    const float* __restrict__ Wih0, const float* __restrict__ Whh0,
    const float* __restrict__ bih0, const float* __restrict__ bhh0,
    const float* __restrict__ Wih1, const float* __restrict__ Whh1,
    const float* __restrict__ bih1, const float* __restrict__ bhh1,
    float* __restrict__ out)
{
    __shared__ __align__(16) _Float16 h1a[2][4 * HSTR];   // [parity][seq*HSTR + elem]
    __shared__ __align__(16) _Float16 h2a[2][4 * HSTR];

    const int tid  = threadIdx.x;
    const int lane = tid & 63;
    const int wid  = tid >> 6;
    const int quad = lane >> 4;
    const int l16  = lane & 15;
    const bool isL1 = (wid >= 4);
    const int wt   = wid & 3;            // elem-tile index
    const int col  = wt * 16 + l16;      // elem column 0..63 this lane owns

    // ---- zero h double-buffers ----
    for (int i = tid; i < 2 * 4 * HSTR; i += 512) {
        ((_Float16*)h1a)[i] = (_Float16)0.0f;
        ((_Float16*)h2a)[i] = (_Float16)0.0f;
    }

    // ---- B-fragments (weights), loaded once; MFMA reads them from AGPR natively ----
    // lane holds W[c*64+col][frag*32 + quad*8 .. +8]  (same convention as R12, proven)
    half8 wfr[4][4];                     // [class][kfrag]; L0 uses kfrag 0..1
    #pragma unroll
    for (int c = 0; c < 4; ++c) {
        const int row = c * 64 + col;
        if (!isL1) {
            #pragma unroll
            for (int f = 0; f < 2; ++f) {
                const float* p = Whh0 + (size_t)row * 64 + f * 32 + quad * 8;
                half8 h;
                #pragma unroll
                for (int u = 0; u < 8; ++u) h[u] = (_Float16)p[u];
                wfr[c][f] = h;
            }
        } else {
            #pragma unroll
            for (int f = 0; f < 4; ++f) {
                const float* base = (f < 2) ? Wih1 : Whh1;
                const float* p = base + (size_t)row * 64 + (f & 1) * 32 + quad * 8;
                half8 h;
                #pragma unroll
                for (int u = 0; u < 8; ++u) h[u] = (_Float16)p[u];
                wfr[c][f] = h;
            }
        }
    }
    // ---- per-lane scalars ----
    float bias[4];
    float wxa[4], wxb[4], wxc[4];        // L0 only
    #pragma unroll
    for (int c = 0; c < 4; ++c) {
        const int row = c * 64 + col;
        if (!isL1) {
            bias[c] = bih0[row] + bhh0[row];
            wxa[c] = Wih0[row*3+0]; wxb[c] = Wih0[row*3+1]; wxc[c] = Wih0[row*3+2];
        } else {
            bias[c] = bih1[row] + bhh1[row];
        }
    }
    // ---- x prefetch (L0 waves only): this lane's seq = quad ----
    const float* xq = x + (size_t)(blockIdx.x * 4 + quad) * TT * 3;
    float xn0 = 0.f, xn1 = 0.f, xn2 = 0.f;
    if (!isL1) { xn0 = xq[0]; xn1 = xq[1]; xn2 = xq[2]; }

    float cst = 0.0f;                    // cell state for (layer, seq=quad, elem=col)

    __syncthreads();

    // iter it: L0 computes step it (it<TT); L1 computes step it-1 (it>=1).
    // h1[t], h2[t] live at parity t&1. ONE barrier per iteration. (R12 scheme.)
    for (int it = 0; it <= TT; ++it) {
        const int cur  = it & 1;
        const int prev = cur ^ 1;

        if (!isL1) {
            if (it < TT) {
                // consume prefetched x[it]; prefetch x[it+1] (clamped)
                const float x0 = xn0, x1 = xn1, x2 = xn2;
                const int nt = (it + 1 < TT) ? it + 1 : TT - 1;
                const float* np = xq + nt * 3;
                xn0 = np[0]; xn1 = np[1]; xn2 = np[2];

                // A-frags: replicated rows, m = l16 -> seq l16&3
                const _Float16* hb = h1a[prev] + (l16 & 3) * HSTR + quad * 8;
                half8 a0 = *(const half8*)hb;
                half8 a1 = *(const half8*)(hb + 32);
                f32x4 acc[4];
                #pragma unroll
                for (int c = 0; c < 4; ++c) {
                    f32x4 z = {0.f, 0.f, 0.f, 0.f};
                    z = __builtin_amdgcn_mfma_f32_16x16x32_f16(a0, wfr[c][0], z, 0, 0, 0);
                    z = __builtin_amdgcn_mfma_f32_16x16x32_f16(a1, wfr[c][1], z, 0, 0, 0);
                    acc[c] = z;
                }
                // in-lane update: reg quad = seq quad (replication), col = this lane's elem
                float pi = sel4(acc[0], quad) + bias[0] + wxa[0]*x0 + wxb[0]*x1 + wxc[0]*x2;
                float pf = sel4(acc[1], quad) + bias[1] + wxa[1]*x0 + wxb[1]*x1 + wxc[1]*x2;
                float pg = sel4(acc[2], quad) + bias[2] + wxa[2]*x0 + wxb[2]*x1 + wxc[2]*x2;
                float po = sel4(acc[3], quad) + bias[3] + wxa[3]*x0 + wxb[3]*x1 + wxc[3]*x2;
                float iv = fast_sigmoid(pi), fv = fast_sigmoid(pf);
                float gv = fast_tanh(pg),    ov = fast_sigmoid(po);
                cst = fmaf(fv, cst, iv * gv);
                h1a[cur][quad * HSTR + col] = (_Float16)(ov * fast_tanh(cst));   // h1[it]
            }
        } else {
            if (it >= 1) {
                // L1 step it-1: K 0..63 from h1[it-1] (parity prev), 64..127 from h2[it-2] (parity cur)
                const _Float16* hb1 = h1a[prev] + (l16 & 3) * HSTR + quad * 8;
                const _Float16* hb2 = h2a[cur]  + (l16 & 3) * HSTR + quad * 8;
                half8 a0 = *(const half8*)hb1;
                half8 a1 = *(const half8*)(hb1 + 32);
                half8 a2 = *(const half8*)hb2;
                half8 a3 = *(const half8*)(hb2 + 32);
                f32x4 acc[4];
                #pragma unroll
                for (int c = 0; c < 4; ++c) {
                    f32x4 z = {0.f, 0.f, 0.f, 0.f};
                    z = __builtin_amdgcn_mfma_f32_16x16x32_f16(a0, wfr[c][0], z, 0, 0, 0);
                    z = __builtin_amdgcn_mfma_f32_16x16x32_f16(a1, wfr[c][1], z, 0, 0, 0);
                    z = __builtin_amdgcn_mfma_f32_16x16x32_f16(a2, wfr[c][2], z, 0, 0, 0);
                    z = __builtin_amdgcn_mfma_f32_16x16x32_f16(a3, wfr[c][3], z, 0, 0, 0);
                    acc[c] = z;
                }
                float pi = sel4(acc[0], quad) + bias[0];
                float pf = sel4(acc[1], quad) + bias[1];
                float pg = sel4(acc[2], quad) + bias[2];
                float po = sel4(acc[3], quad) + bias[3];
                float iv = fast_sigmoid(pi), fv = fast_sigmoid(pf);
                float gv = fast_tanh(pg),    ov = fast_sigmoid(po);
                cst = fmaf(fv, cst, iv * gv);
                float hv = ov * fast_tanh(cst);
                h2a[prev][quad * HSTR + col] = (_Float16)hv;                     // h2[it-1]
                if (it == TT)
                    out[(size_t)(blockIdx.x * 4 + quad) * 64 + col] = hv;
            }
        }
        __syncthreads();
    }
}

extern "C" void kernel_launch(void* const* d_in, const int* in_sizes, int n_in,
                              void* d_out, int out_size, void* d_ws, size_t ws_size,
                              hipStream_t stream) {
    const float* x    = (const float*)d_in[0];
    const float* Wih0 = (const float*)d_in[1];
    const float* Whh0 = (const float*)d_in[2];
    const float* bih0 = (const float*)d_in[3];
    const float* bhh0 = (const float*)d_in[4];
    const float* Wih1 = (const float*)d_in[5];
    const float* Whh1 = (const float*)d_in[6];
    const float* bih1 = (const float*)d_in[7];
    const float* bhh1 = (const float*)d_in[8];
    float* out = (float*)d_out;

    // 512 sequences / 4 per block = 128 blocks; 512 threads (8 waves).
    lstm2_fused<<<128, 512, 0, stream>>>(x, Wih0, Whh0, bih0, bhh0,
                                         Wih1, Whh1, bih1, bhh1, out);
}